// Round 1
// baseline (6990.221 us; speedup 1.0000x reference)
//
#include <hip/hip_runtime.h>

// Problem constants
#define N_BATCH   64
#define C_IN      128
#define C_MID     256
#define H_IN      56
#define W_IN      56
#define H_OUT     28
#define W_OUT     28
#define SPATIAL   (H_OUT*W_OUT)          // 784
#define OUT_ELEMS (N_BATCH*C_MID*SPATIAL) // 12,845,056

#define HISTBINS  (1<<20)
#define RANGE_LO  (-16.0f)
#define INV_WIDTH 32768.0f               // bins per unit; width = 1/32768

// ---------------------------------------------------------------------------
// conv1: x[64,128,56,56] * w1[256,128,3,3], stride 2, pad 1 -> out1[64,256,28,28]
// Block: (n, cout-group of 8). 256 threads; each thread: 4 spatial x 8 cout accs.
// Weights staged per 64-cin chunk in LDS, broadcast-read as float4.
// ---------------------------------------------------------------------------
__global__ __launch_bounds__(256) void conv1_kernel(
    const float* __restrict__ x, const float* __restrict__ w1,
    float* __restrict__ out1)
{
    const int n     = blockIdx.x;
    const int cout0 = blockIdx.y * 8;
    const int tid   = threadIdx.x;

    __shared__ float wl[64 * 9 * 8];   // [cin_local][k][co] — 18 KB

    float acc[4][8];
    #pragma unroll
    for (int i = 0; i < 4; ++i)
        #pragma unroll
        for (int co = 0; co < 8; ++co) acc[i][co] = 0.f;

    int hh[4], ww[4]; bool vv[4];
    #pragma unroll
    for (int i = 0; i < 4; ++i) {
        int s = tid + i * 256;
        vv[i] = (s < SPATIAL);
        if (s > SPATIAL - 1) s = SPATIAL - 1;
        hh[i] = s / W_OUT; ww[i] = s - hh[i] * W_OUT;
    }

    for (int c0 = 0; c0 < C_IN; c0 += 64) {
        for (int idx = tid; idx < 64 * 9 * 8; idx += 256) {
            int co = idx & 7; int rest = idx >> 3;
            int cl = rest / 9; int k = rest - cl * 9;
            wl[idx] = w1[((cout0 + co) * C_IN + (c0 + cl)) * 9 + k];
        }
        __syncthreads();

        for (int cl = 0; cl < 64; ++cl) {
            const float* xp = x + (size_t)(n * C_IN + c0 + cl) * (H_IN * W_IN);
            float xv[4][9];
            #pragma unroll
            for (int i = 0; i < 4; ++i) {
                int ih0 = 2 * hh[i] - 1, iw0 = 2 * ww[i] - 1;
                #pragma unroll
                for (int kh = 0; kh < 3; ++kh) {
                    int ih = ih0 + kh;
                    #pragma unroll
                    for (int kw = 0; kw < 3; ++kw) {
                        int iw = iw0 + kw;
                        bool ok = vv[i] && (ih >= 0) && (iw >= 0) && (ih < H_IN) && (iw < W_IN);
                        xv[i][kh * 3 + kw] = ok ? xp[ih * W_IN + iw] : 0.f;
                    }
                }
            }
            #pragma unroll
            for (int k = 0; k < 9; ++k) {
                const float4* wp = (const float4*)&wl[(cl * 9 + k) * 8];
                float4 wa = wp[0], wb = wp[1];
                #pragma unroll
                for (int i = 0; i < 4; ++i) {
                    float xs = xv[i][k];
                    acc[i][0] += xs * wa.x; acc[i][1] += xs * wa.y;
                    acc[i][2] += xs * wa.z; acc[i][3] += xs * wa.w;
                    acc[i][4] += xs * wb.x; acc[i][5] += xs * wb.y;
                    acc[i][6] += xs * wb.z; acc[i][7] += xs * wb.w;
                }
            }
        }
        __syncthreads();
    }

    #pragma unroll
    for (int i = 0; i < 4; ++i) {
        if (!vv[i]) continue;
        int s = tid + i * 256;
        #pragma unroll
        for (int co = 0; co < 8; ++co)
            out1[(size_t)(n * C_MID + cout0 + co) * SPATIAL + s] = acc[i][co];
    }
}

// ---------------------------------------------------------------------------
// conv2 + identity conv + residual add (writes PRE-clamp result):
//   out[n,co,h,w] = sum_cin clamp01(out1)[n,cin, h-1+kh, w-1+kw] * w2[co,cin,kh,kw]
//                 + sum_cin x[n,cin, 2h, 2w] * wid[co,cin]
// ---------------------------------------------------------------------------
__global__ __launch_bounds__(256) void conv2_kernel(
    const float* __restrict__ out1, const float* __restrict__ x,
    const float* __restrict__ w2, const float* __restrict__ wid,
    float* __restrict__ outp)
{
    const int n     = blockIdx.x;
    const int cout0 = blockIdx.y * 8;
    const int tid   = threadIdx.x;

    __shared__ float wl[64 * 9 * 8];   // 18 KB
    __shared__ float widl[128 * 8];    // 4 KB

    float acc[4][8];
    #pragma unroll
    for (int i = 0; i < 4; ++i)
        #pragma unroll
        for (int co = 0; co < 8; ++co) acc[i][co] = 0.f;

    int hh[4], ww[4]; bool vv[4];
    #pragma unroll
    for (int i = 0; i < 4; ++i) {
        int s = tid + i * 256;
        vv[i] = (s < SPATIAL);
        if (s > SPATIAL - 1) s = SPATIAL - 1;
        hh[i] = s / W_OUT; ww[i] = s - hh[i] * W_OUT;
    }

    for (int c0 = 0; c0 < C_MID; c0 += 64) {
        for (int idx = tid; idx < 64 * 9 * 8; idx += 256) {
            int co = idx & 7; int rest = idx >> 3;
            int cl = rest / 9; int k = rest - cl * 9;
            wl[idx] = w2[((cout0 + co) * C_MID + (c0 + cl)) * 9 + k];
        }
        __syncthreads();

        for (int cl = 0; cl < 64; ++cl) {
            const float* ip = out1 + (size_t)(n * C_MID + c0 + cl) * SPATIAL;
            float xv[4][9];
            #pragma unroll
            for (int i = 0; i < 4; ++i) {
                int ih0 = hh[i] - 1, iw0 = ww[i] - 1;
                #pragma unroll
                for (int kh = 0; kh < 3; ++kh) {
                    int ih = ih0 + kh;
                    #pragma unroll
                    for (int kw = 0; kw < 3; ++kw) {
                        int iw = iw0 + kw;
                        bool ok = vv[i] && (ih >= 0) && (iw >= 0) && (ih < H_OUT) && (iw < W_OUT);
                        float v = ok ? ip[ih * W_OUT + iw] : 0.f;
                        v = fminf(fmaxf(v, 0.f), 1.0f);   // clamp01 of conv1 output
                        xv[i][kh * 3 + kw] = v;
                    }
                }
            }
            #pragma unroll
            for (int k = 0; k < 9; ++k) {
                const float4* wp = (const float4*)&wl[(cl * 9 + k) * 8];
                float4 wa = wp[0], wb = wp[1];
                #pragma unroll
                for (int i = 0; i < 4; ++i) {
                    float xs = xv[i][k];
                    acc[i][0] += xs * wa.x; acc[i][1] += xs * wa.y;
                    acc[i][2] += xs * wa.z; acc[i][3] += xs * wa.w;
                    acc[i][4] += xs * wb.x; acc[i][5] += xs * wb.y;
                    acc[i][6] += xs * wb.z; acc[i][7] += xs * wb.w;
                }
            }
        }
        __syncthreads();
    }

    // identity 1x1 stride-2 conv on raw x
    for (int idx = tid; idx < 128 * 8; idx += 256) {
        int co = idx & 7; int cl = idx >> 3;
        widl[idx] = wid[(cout0 + co) * C_IN + cl];
    }
    __syncthreads();

    for (int cin = 0; cin < C_IN; ++cin) {
        const float* xp = x + (size_t)(n * C_IN + cin) * (H_IN * W_IN);
        float xs[4];
        #pragma unroll
        for (int i = 0; i < 4; ++i)
            xs[i] = vv[i] ? xp[(2 * hh[i]) * W_IN + 2 * ww[i]] : 0.f;
        const float4* wp = (const float4*)&widl[cin * 8];
        float4 wa = wp[0], wb = wp[1];
        #pragma unroll
        for (int i = 0; i < 4; ++i) {
            acc[i][0] += xs[i] * wa.x; acc[i][1] += xs[i] * wa.y;
            acc[i][2] += xs[i] * wa.z; acc[i][3] += xs[i] * wa.w;
            acc[i][4] += xs[i] * wb.x; acc[i][5] += xs[i] * wb.y;
            acc[i][6] += xs[i] * wb.z; acc[i][7] += xs[i] * wb.w;
        }
    }

    #pragma unroll
    for (int i = 0; i < 4; ++i) {
        if (!vv[i]) continue;
        int s = tid + i * 256;
        #pragma unroll
        for (int co = 0; co < 8; ++co)
            outp[(size_t)(n * C_MID + cout0 + co) * SPATIAL + s] = acc[i][co];
    }
}

// ---------------------------------------------------------------------------
// Histogram over fixed range [-16, 16), 2^20 bins
// ---------------------------------------------------------------------------
__global__ void hist_kernel(const float* __restrict__ src, int n4,
                            unsigned int* __restrict__ hist)
{
    int idx = blockIdx.x * blockDim.x + threadIdx.x;
    int stride = gridDim.x * blockDim.x;
    const float4* s4 = (const float4*)src;
    for (int i = idx; i < n4; i += stride) {
        float4 v = s4[i];
        float f[4] = {v.x, v.y, v.z, v.w};
        #pragma unroll
        for (int j = 0; j < 4; ++j) {
            int b = (int)((f[j] - RANGE_LO) * INV_WIDTH);
            b = min(max(b, 0), HISTBINS - 1);
            atomicAdd(&hist[b], 1u);
        }
    }
}

// ---------------------------------------------------------------------------
// Select the 99 percentile values from the histogram.
// k (1-based) = 1 + rint(0.01*q*(n-1))  — matches Python round (half-even).
// ---------------------------------------------------------------------------
__global__ __launch_bounds__(1024) void select_kernel(
    const unsigned int* __restrict__ hist, float* __restrict__ outp)
{
    __shared__ unsigned int csum[1024];   // inclusive per-chunk sums
    const int tid = threadIdx.x;

    unsigned int s = 0;
    const unsigned int* h = hist + (size_t)tid * 1024;
    for (int i = 0; i < 1024; ++i) s += h[i];
    csum[tid] = s;
    __syncthreads();

    if (tid == 0) {
        unsigned int run = 0;
        for (int i = 0; i < 1024; ++i) { run += csum[i]; csum[i] = run; }
    }
    __syncthreads();

    if (tid >= 1 && tid <= 99) {
        const int q = tid;
        long long k = 1 + (long long)llrint(0.01 * (double)q * (double)(OUT_ELEMS - 1));
        int c = 0;
        while ((long long)csum[c] < k) ++c;
        long long cum = (c == 0) ? 0 : (long long)csum[c - 1];
        int b = c * 1024;
        while (cum + (long long)hist[b] < k) { cum += hist[b]; ++b; }
        outp[q - 1] = RANGE_LO + ((float)b + 0.5f) * (1.0f / INV_WIDTH);
    }
}

// ---------------------------------------------------------------------------
// In-place clamp to [0, 1]
// ---------------------------------------------------------------------------
__global__ void clamp_kernel(float* __restrict__ p, int n4)
{
    int idx = blockIdx.x * blockDim.x + threadIdx.x;
    int stride = gridDim.x * blockDim.x;
    float4* p4 = (float4*)p;
    for (int i = idx; i < n4; i += stride) {
        float4 v = p4[i];
        v.x = fminf(fmaxf(v.x, 0.f), 1.f);
        v.y = fminf(fmaxf(v.y, 0.f), 1.f);
        v.z = fminf(fmaxf(v.z, 0.f), 1.f);
        v.w = fminf(fmaxf(v.w, 0.f), 1.f);
        p4[i] = v;
    }
}

// ---------------------------------------------------------------------------
extern "C" void kernel_launch(void* const* d_in, const int* in_sizes, int n_in,
                              void* d_out, int out_size, void* d_ws, size_t ws_size,
                              hipStream_t stream)
{
    const float* x   = (const float*)d_in[0];
    const float* w1  = (const float*)d_in[1];
    const float* w2  = (const float*)d_in[2];
    const float* wid = (const float*)d_in[3];
    float* out = (float*)d_out;

    float* out1 = (float*)d_ws;                                  // 51.38 MB
    unsigned int* histA = (unsigned int*)((char*)d_ws + (size_t)OUT_ELEMS * 4);
    unsigned int* histB = histA + HISTBINS;                      // 4 MB each

    // zero both histograms (ws is poisoned 0xAA before every launch)
    hipMemsetAsync(histA, 0, (size_t)HISTBINS * 2 * sizeof(unsigned int), stream);

    conv1_kernel<<<dim3(N_BATCH, C_MID / 8), 256, 0, stream>>>(x, w1, out1);
    hist_kernel<<<2048, 256, 0, stream>>>(out1, OUT_ELEMS / 4, histA);
    select_kernel<<<1, 1024, 0, stream>>>(histA, out + OUT_ELEMS);

    conv2_kernel<<<dim3(N_BATCH, C_MID / 8), 256, 0, stream>>>(out1, x, w2, wid, out);
    hist_kernel<<<2048, 256, 0, stream>>>(out, OUT_ELEMS / 4, histB);
    select_kernel<<<1, 1024, 0, stream>>>(histB, out + OUT_ELEMS + 99);

    clamp_kernel<<<2048, 256, 0, stream>>>(out, OUT_ELEMS / 4);
}

// Round 2
// 520.093 us; speedup vs baseline: 13.4403x; 13.4403x over previous
//
#include <hip/hip_runtime.h>

typedef unsigned short ushort_t;
typedef unsigned int uint_t;

using short8 = __attribute__((ext_vector_type(8))) short;
using f32x4  = __attribute__((ext_vector_type(4))) float;

#define N_BATCH   64
#define C_MID     256
#define H_OUT     28
#define W_OUT     28
#define SPATIAL   (H_OUT*W_OUT)
#define OUT_ELEMS (N_BATCH*C_MID*SPATIAL)   // 12,845,056

// histogram: 4096 bins over [-16,16), width 1/128
#define NBINS 4096
#define BIN_LO (-16.0f)
#define BIN_INV 128.0f
#define BIN_W  0.0078125f

// padded channels-last geometry (u16 element units)
#define XT_ROW   (57*128)        // 7296
#define XT_IMG   (57*57*128)     // 415872
#define O1_ROW   (30*256)        // 7680
#define O1_IMG   (30*30*256)     // 230400

__device__ __forceinline__ ushort_t f2bf(float f) {
    uint_t u = __float_as_uint(f);
    u += 0x7FFFu + ((u >> 16) & 1u);
    return (ushort_t)(u >> 16);
}

__device__ __forceinline__ void gll16(const ushort_t* g, void* l) {
    __builtin_amdgcn_global_load_lds(
        (const __attribute__((address_space(1))) unsigned int*)g,
        (__attribute__((address_space(3))) unsigned int*)l, 16, 0, 0);
}

// ---------------------------------------------------------------------------
// Weight transform: wT1[co][(kh*3+kw)*128+ci] ; wT2[co][k] with k<2304 from w2
// ((kh*3+kw)*256+ci) and k in [2304,2432) = wid[co][ci].  bf16.
// ---------------------------------------------------------------------------
__global__ __launch_bounds__(256) void wtrans(
    const float* __restrict__ w1, const float* __restrict__ w2,
    const float* __restrict__ wid, ushort_t* __restrict__ wT1,
    ushort_t* __restrict__ wT2)
{
    int idx = blockIdx.x * 256 + threadIdx.x;
    if (idx < 256 * 1152) {
        int co = idx / 1152, k = idx % 1152;
        int g = k >> 7, ci = k & 127;
        wT1[idx] = f2bf(w1[(co * 128 + ci) * 9 + g]);
    }
    if (idx < 256 * 2432) {
        int co = idx / 2432, k = idx % 2432;
        float v;
        if (k < 2304) { int g = k >> 8, ci = k & 255; v = w2[(co * 256 + ci) * 9 + g]; }
        else          { v = wid[co * 128 + (k - 2304)]; }
        wT2[idx] = f2bf(v);
    }
}

// ---------------------------------------------------------------------------
// x transform: NCHW f32 -> padded channels-last bf16 xT[n][1+ih][1+iw][ci]
// block = (g=row-group of 4, n). LDS transpose for coalesced 256B writes.
// ---------------------------------------------------------------------------
__global__ __launch_bounds__(256) void xtrans(
    const float* __restrict__ x, ushort_t* __restrict__ xT)
{
    __shared__ ushort_t t[224 * 130];
    const int tid = threadIdx.x;
    const int g = blockIdx.x, n = blockIdx.y;
    const float* xs = x + ((size_t)n * 128) * 3136 + g * 4 * 56;

    for (int it = 0; it < 112; ++it) {
        int f = it * 256 + tid;            // 0..28671
        int ci = f / 224, rem = f % 224;   // rem = r*56+iw
        t[rem * 130 + ci] = f2bf(xs[ci * 3136 + rem]);
    }
    __syncthreads();
    ushort_t* xo = xT + (size_t)n * XT_IMG + (g * 4 + 1) * XT_ROW + 128;
    for (int it = 0; it < 56; ++it) {
        int f = it * 256 + tid;            // 0..14335
        int pos = f >> 6, c2 = f & 63;
        int r = pos / 56, iw = pos % 56;
        uint_t v = *(const uint_t*)&t[pos * 130 + c2 * 2];
        *(uint_t*)(xo + r * XT_ROW + iw * 128 + c2 * 2) = v;
    }
}

// ---------------------------------------------------------------------------
// MFMA implicit-GEMM conv. CONV=1: conv1 (B=xT stride2, K=1152), epilogue:
// hist(raw) + clamp -> bf16 o1T.  CONV=2: conv2 (B=o1T, K=2304) + fused
// identity (2 stages from xT), epilogue: hist(raw) + clamp -> f32 out.
// Tile: 128co x 112pos, BK=64, 4 waves of 32co x 112pos.
// ---------------------------------------------------------------------------
template <int CONV>
__global__ __launch_bounds__(256) void gemm_conv(
    const ushort_t* __restrict__ Bsrc, const ushort_t* __restrict__ xTp,
    const ushort_t* __restrict__ wT, ushort_t* __restrict__ o1T,
    float* __restrict__ fout, ushort_t* __restrict__ bh)
{
    constexpr int KROW = (CONV == 1) ? 1152 : 2432;
    constexpr int NST  = (CONV == 1) ? 18 : 38;
    constexpr int BIMG = (CONV == 1) ? XT_IMG : O1_IMG;

    const int bx = blockIdx.x;          // 0..447
    const int by = blockIdx.y;          // 0..1
    const int tid = threadIdx.x;
    const int wv = tid >> 6, lane = tid & 63;
    const int ln = lane & 15, quad = lane >> 4;
    const int n = bx / 7, rg = bx % 7, h0 = rg * 4;

    __shared__ short8 Ald[8 * 128];     // [k8][co]  16 KB
    __shared__ short8 Bld[8 * 112];     // [k8][pos] 14 KB
    __shared__ uint_t hist[NBINS];      // 16 KB

    for (int i = tid; i < NBINS; i += 256) hist[i] = 0;

    f32x4 acc[2][7];
    #pragma unroll
    for (int a = 0; a < 2; ++a)
        #pragma unroll
        for (int b = 0; b < 7; ++b) acc[a][b] = (f32x4){0.f, 0.f, 0.f, 0.f};

    // B staging per-lane constants: inst = wv + 4j ; flat = inst*64+lane
    uint_t pk8[4], ppos[4], boff[4];
    #pragma unroll
    for (int j = 0; j < 4; ++j) {
        int inst = wv + 4 * j;
        int flat = inst * 64 + lane;
        int k8 = flat / 112, pos = flat % 112;
        pk8[j] = k8; ppos[j] = pos;
        int hh = h0 + pos / 28, w = pos % 28;
        if (CONV == 1) boff[j] = (uint_t)((2 * hh) * XT_ROW + (2 * w) * 128 + k8 * 8);
        else           boff[j] = (uint_t)(hh * O1_ROW + w * 256 + k8 * 8);
    }
    // A staging: inst = wv*4+j ; co = (j&1)*64+lane ; k8 = wv*2+(j>>1)
    const ushort_t* Abase = wT + (size_t)(by * 128 + lane) * KROW;

    const ushort_t* Bimg = Bsrc + (size_t)n * BIMG;
    const ushort_t* Ximg = xTp + (size_t)n * XT_IMG;

    for (int s = 0; s < NST; ++s) {
        const int k0 = s * 64;
        const bool id = (CONV == 2) && (s >= 36);
        uint_t bso = 0;
        const ushort_t* bp;
        if (id) {
            bp = Ximg;
        } else {
            int g   = (CONV == 1) ? (s >> 1) : (s >> 2);
            int ci0 = (CONV == 1) ? ((s & 1) << 6) : ((s & 3) << 6);
            int kh = g / 3, kw = g % 3;
            bso = (CONV == 1) ? (uint_t)((kh * 57 + kw) * 128 + ci0)
                              : (uint_t)((kh * 30 + kw) * 256 + ci0);
            bp = Bimg;
        }
        __syncthreads();   // previous compute done before LDS overwrite
        #pragma unroll
        for (int j = 0; j < 4; ++j) {
            gll16(Abase + (j & 1) * 64 * KROW + (wv * 2 + (j >> 1)) * 8 + k0,
                  (char*)Ald + (wv * 4 + j) * 1024);
        }
        #pragma unroll
        for (int j = 0; j < 4; ++j) {
            int inst = wv + 4 * j;
            if (inst < 14) {
                uint_t off;
                if (id) {
                    int pos = ppos[j];
                    int hh = h0 + pos / 28, w = pos % 28;
                    off = (uint_t)(((2 * hh + 1) * 57 + (2 * w + 1)) * 128 +
                                   pk8[j] * 8 + ((s - 36) << 6));
                } else {
                    off = boff[j] + bso;
                }
                gll16(bp + off, (char*)Bld + inst * 1024);
            }
        }
        __syncthreads();   // drains vmcnt -> staged data visible

        #pragma unroll
        for (int kk = 0; kk < 2; ++kk) {
            short8 af[2], bf[7];
            #pragma unroll
            for (int a = 0; a < 2; ++a)
                af[a] = Ald[(kk * 4 + quad) * 128 + wv * 32 + a * 16 + ln];
            #pragma unroll
            for (int b = 0; b < 7; ++b)
                bf[b] = Bld[(kk * 4 + quad) * 112 + b * 16 + ln];
            #pragma unroll
            for (int a = 0; a < 2; ++a)
                #pragma unroll
                for (int b = 0; b < 7; ++b)
                    acc[a][b] = __builtin_amdgcn_mfma_f32_16x16x32_bf16(
                        af[a], bf[b], acc[a][b], 0, 0, 0);
        }
    }

    // ---- epilogue ----
    int hq[7], wq[7];
    #pragma unroll
    for (int b = 0; b < 7; ++b) {
        int pos = b * 16 + ln;
        hq[b] = h0 + pos / 28; wq[b] = pos % 28;
    }

    if (CONV == 1) {
        ushort_t* oimg = o1T + (size_t)n * O1_IMG;
        #pragma unroll
        for (int a = 0; a < 2; ++a) {
            int co = by * 128 + wv * 32 + a * 16 + quad * 4;
            #pragma unroll
            for (int b = 0; b < 7; ++b) {
                ushort_t pk[4];
                #pragma unroll
                for (int r = 0; r < 4; ++r) {
                    float v = acc[a][b][r];
                    int bin = (int)((v - BIN_LO) * BIN_INV);
                    bin = min(max(bin, 0), NBINS - 1);
                    atomicAdd(&hist[bin], 1u);
                    pk[r] = f2bf(fminf(fmaxf(v, 0.f), 1.f));
                }
                uint2 u; u.x = (uint_t)pk[0] | ((uint_t)pk[1] << 16);
                u.y = (uint_t)pk[2] | ((uint_t)pk[3] << 16);
                *(uint2*)(oimg + ((hq[b] + 1) * 30 + (wq[b] + 1)) * 256 + co) = u;
            }
        }
    } else {
        #pragma unroll
        for (int a = 0; a < 2; ++a) {
            #pragma unroll
            for (int b = 0; b < 7; ++b) {
                int pos = b * 16 + ln;
                #pragma unroll
                for (int r = 0; r < 4; ++r) {
                    float v = acc[a][b][r];
                    int bin = (int)((v - BIN_LO) * BIN_INV);
                    bin = min(max(bin, 0), NBINS - 1);
                    atomicAdd(&hist[bin], 1u);
                    int co = by * 128 + wv * 32 + a * 16 + quad * 4 + r;
                    fout[((size_t)(n * 256 + co)) * SPATIAL + h0 * 28 + pos] =
                        fminf(fmaxf(v, 0.f), 1.f);
                }
            }
        }
    }

    __syncthreads();
    size_t blin = (size_t)(by * 448 + bx) * NBINS;
    for (int i = tid; i < NBINS; i += 256) bh[blin + i] = (ushort_t)hist[i];
}

// ---------------------------------------------------------------------------
// Reduce 896 per-block u16 histograms -> final u32 histogram
// ---------------------------------------------------------------------------
__global__ __launch_bounds__(256) void hreduce(
    const ushort_t* __restrict__ bh, uint_t* __restrict__ hf)
{
    __shared__ uint_t p[256];
    int b0 = blockIdx.x * 64;
    int binl = threadIdx.x & 63, grp = threadIdx.x >> 6;
    uint_t s = 0;
    for (int j = grp; j < 896; j += 4) s += bh[(size_t)j * NBINS + b0 + binl];
    p[threadIdx.x] = s;
    __syncthreads();
    if (threadIdx.x < 64)
        hf[b0 + threadIdx.x] = p[threadIdx.x] + p[64 + threadIdx.x] +
                               p[128 + threadIdx.x] + p[192 + threadIdx.x];
}

// ---------------------------------------------------------------------------
// Select 99 percentile values from the 4096-bin histogram
// ---------------------------------------------------------------------------
__global__ __launch_bounds__(1024) void select_k(
    const uint_t* __restrict__ hf, float* __restrict__ outp)
{
    __shared__ uint_t cs[1024];
    int t = threadIdx.x;
    uint_t s = hf[4 * t] + hf[4 * t + 1] + hf[4 * t + 2] + hf[4 * t + 3];
    cs[t] = s;
    __syncthreads();
    for (int d = 1; d < 1024; d <<= 1) {
        uint_t v = (t >= d) ? cs[t - d] : 0;
        __syncthreads();
        cs[t] += v;
        __syncthreads();
    }
    if (t >= 1 && t <= 99) {
        long long k = 1 + (long long)llrint(0.01 * (double)t * (double)(OUT_ELEMS - 1));
        int lo = 0, hi = 1023;
        while (lo < hi) { int mid = (lo + hi) >> 1; if ((long long)cs[mid] < k) lo = mid + 1; else hi = mid; }
        long long cum = (lo == 0) ? 0 : (long long)cs[lo - 1];
        int b = lo * 4;
        while (cum + (long long)hf[b] < k) { cum += hf[b]; ++b; }
        outp[t - 1] = BIN_LO + ((float)b + 0.5f) * BIN_W;
    }
}

// ---------------------------------------------------------------------------
extern "C" void kernel_launch(void* const* d_in, const int* in_sizes, int n_in,
                              void* d_out, int out_size, void* d_ws, size_t ws_size,
                              hipStream_t stream)
{
    const float* x   = (const float*)d_in[0];
    const float* w1  = (const float*)d_in[1];
    const float* w2  = (const float*)d_in[2];
    const float* wid = (const float*)d_in[3];
    float* out = (float*)d_out;

    char* ws = (char*)d_ws;
    ushort_t* xT  = (ushort_t*)ws;                         // 53,231,616 B
    ushort_t* o1T = (ushort_t*)(ws + 53231616);            // 29,491,200 B
    ushort_t* wT1 = (ushort_t*)(ws + 82722816);            //    589,824 B
    ushort_t* wT2 = (ushort_t*)(ws + 83312640);            //  1,245,184 B
    ushort_t* bh  = (ushort_t*)(ws + 84557824);            //  7,340,032 B
    uint_t*   hf  = (uint_t*)  (ws + 91897856);            //     16,384 B
    // total 91,914,240 B

    hipMemsetAsync(xT, 0, 53231616, stream);
    hipMemsetAsync(o1T, 0, 29491200, stream);

    wtrans<<<2432, 256, 0, stream>>>(w1, w2, wid, wT1, wT2);
    xtrans<<<dim3(14, 64), 256, 0, stream>>>(x, xT);

    gemm_conv<1><<<dim3(448, 2), 256, 0, stream>>>(xT, xT, wT1, o1T, nullptr, bh);
    hreduce<<<64, 256, 0, stream>>>(bh, hf);
    select_k<<<1, 1024, 0, stream>>>(hf, out + OUT_ELEMS);

    gemm_conv<2><<<dim3(448, 2), 256, 0, stream>>>(o1T, xT, wT2, nullptr, out, bh);
    hreduce<<<64, 256, 0, stream>>>(bh, hf);
    select_k<<<1, 1024, 0, stream>>>(hf, out + OUT_ELEMS + 99);
}

// Round 3
// 467.150 us; speedup vs baseline: 14.9636x; 1.1133x over previous
//
#include <hip/hip_runtime.h>

typedef unsigned short ushort_t;
typedef unsigned int uint_t;

using short8 = __attribute__((ext_vector_type(8))) short;
using f32x4  = __attribute__((ext_vector_type(4))) float;

#define N_BATCH   64
#define C_MID     256
#define H_OUT     28
#define W_OUT     28
#define SPATIAL   (H_OUT*W_OUT)
#define OUT_ELEMS (N_BATCH*C_MID*SPATIAL)   // 12,845,056

// histogram: 2048 bins over [-16,16), width 1/64
#define NBINS 2048
#define BIN_LO (-16.0f)
#define BIN_INV 64.0f
#define BIN_W  0.015625f

// padded channels-last geometry (u16 element units)
#define XT_ROW   (57*128)        // 7296
#define XT_IMG   (57*57*128)     // 415872
#define O1_ROW   (30*256)        // 7680
#define O1_IMG   (30*30*256)     // 230400

__device__ __forceinline__ ushort_t f2bf(float f) {
    uint_t u = __float_as_uint(f);
    u += 0x7FFFu + ((u >> 16) & 1u);
    return (ushort_t)(u >> 16);
}

__device__ __forceinline__ void gll16(const ushort_t* g, void* l) {
    __builtin_amdgcn_global_load_lds(
        (const __attribute__((address_space(1))) unsigned int*)g,
        (__attribute__((address_space(3))) unsigned int*)l, 16, 0, 0);
}

// ---------------------------------------------------------------------------
// Weight transform: wT1[co][(kh*3+kw)*128+ci] ; wT2[co][k] with k<2304 from w2
// ((kh*3+kw)*256+ci) and k in [2304,2432) = wid[co][ci].  bf16.
// ---------------------------------------------------------------------------
__global__ __launch_bounds__(256) void wtrans(
    const float* __restrict__ w1, const float* __restrict__ w2,
    const float* __restrict__ wid, ushort_t* __restrict__ wT1,
    ushort_t* __restrict__ wT2)
{
    int idx = blockIdx.x * 256 + threadIdx.x;
    if (idx < 256 * 1152) {
        int co = idx / 1152, k = idx % 1152;
        int g = k >> 7, ci = k & 127;
        wT1[idx] = f2bf(w1[(co * 128 + ci) * 9 + g]);
    }
    if (idx < 256 * 2432) {
        int co = idx / 2432, k = idx % 2432;
        float v;
        if (k < 2304) { int g = k >> 8, ci = k & 255; v = w2[(co * 256 + ci) * 9 + g]; }
        else          { v = wid[co * 128 + (k - 2304)]; }
        wT2[idx] = f2bf(v);
    }
}

// ---------------------------------------------------------------------------
// x transform: NCHW f32 -> padded channels-last bf16 xT[n][1+ih][1+iw][ci]
// ---------------------------------------------------------------------------
__global__ __launch_bounds__(256) void xtrans(
    const float* __restrict__ x, ushort_t* __restrict__ xT)
{
    __shared__ ushort_t t[224 * 130];
    const int tid = threadIdx.x;
    const int g = blockIdx.x, n = blockIdx.y;
    const float* xs = x + ((size_t)n * 128) * 3136 + g * 4 * 56;

    for (int it = 0; it < 112; ++it) {
        int f = it * 256 + tid;
        int ci = f / 224, rem = f % 224;
        t[rem * 130 + ci] = f2bf(xs[ci * 3136 + rem]);
    }
    __syncthreads();
    ushort_t* xo = xT + (size_t)n * XT_IMG + (g * 4 + 1) * XT_ROW + 128;
    for (int it = 0; it < 56; ++it) {
        int f = it * 256 + tid;
        int pos = f >> 6, c2 = f & 63;
        int r = pos / 56, iw = pos % 56;
        uint_t v = *(const uint_t*)&t[pos * 130 + c2 * 2];
        *(uint_t*)(xo + r * XT_ROW + iw * 128 + c2 * 2) = v;
    }
}

// ---------------------------------------------------------------------------
// conv1: 128co-half x 112pos tile, 18 stages (9 taps x 2 ci-halves), A+B
// double-buffered, single barrier per stage with prefetch-after-barrier.
// ---------------------------------------------------------------------------
__global__ __launch_bounds__(256, 2) void conv1_mfma(
    const ushort_t* __restrict__ xT, const ushort_t* __restrict__ wT1,
    ushort_t* __restrict__ o1T, ushort_t* __restrict__ bh)
{
    const int bx = blockIdx.x, by = blockIdx.y;
    const int tid = threadIdx.x;
    const int wv = tid >> 6, lane = tid & 63;
    const int ln = lane & 15, quad = lane >> 4;
    const int n = bx / 7, rg = bx % 7, h0 = rg * 4;

    __shared__ short8 Ald[2 * 1024];    // 32 KB
    __shared__ short8 Bld[2 * 896];     // 28 KB
    __shared__ uint_t hist[NBINS];      // 8 KB

    for (int i = tid; i < NBINS; i += 256) hist[i] = 0;

    f32x4 acc[2][7];
    #pragma unroll
    for (int a = 0; a < 2; ++a)
        #pragma unroll
        for (int b = 0; b < 7; ++b) acc[a][b] = (f32x4){0.f, 0.f, 0.f, 0.f};

    // B staging per-lane constants: inst = wv + 4j ; flat = inst*64+lane
    uint_t boff[4]; int bok[4];
    #pragma unroll
    for (int j = 0; j < 4; ++j) {
        int inst = wv + 4 * j;
        int flat = inst * 64 + lane;
        int k8 = flat / 112, pos = flat % 112;
        bok[j] = (inst < 14);
        int hh = h0 + pos / 28, w = pos % 28;
        boff[j] = (uint_t)((2 * hh) * XT_ROW + (2 * w) * 128 + k8 * 8);
    }
    const ushort_t* Abase = wT1 + (size_t)(by * 128 + lane) * 1152;
    const ushort_t* Bimg = xT + (size_t)n * XT_IMG;

    auto stageA = [&](int k0, int buf) {
        #pragma unroll
        for (int j = 0; j < 4; ++j)
            gll16(Abase + (j & 1) * 64 * 1152 + (wv * 2 + (j >> 1)) * 8 + k0,
                  (char*)Ald + buf * 16384 + (wv * 4 + j) * 1024);
    };
    auto stageB = [&](int bso, int buf) {
        #pragma unroll
        for (int j = 0; j < 4; ++j)
            if (bok[j])
                gll16(Bimg + boff[j] + bso,
                      (char*)Bld + buf * 14336 + (wv + 4 * j) * 1024);
    };

    stageA(0, 0);
    stageB(0, 0);
    __syncthreads();

    for (int s = 0; s < 18; ++s) {
        if (s < 17) {
            int s1 = s + 1;
            int g = s1 >> 1, ci0 = (s1 & 1) << 6;
            int kh = g / 3, kw = g % 3;
            stageA(s1 * 64, s1 & 1);
            stageB((kh * 57 + kw) * 128 + ci0, s1 & 1);
        }
        const int ab = (s & 1) * 1024, bb = (s & 1) * 896;
        #pragma unroll
        for (int kk = 0; kk < 2; ++kk) {
            short8 af[2], bf[7];
            #pragma unroll
            for (int a = 0; a < 2; ++a)
                af[a] = Ald[ab + (kk * 4 + quad) * 128 + wv * 32 + a * 16 + ln];
            #pragma unroll
            for (int b = 0; b < 7; ++b)
                bf[b] = Bld[bb + (kk * 4 + quad) * 112 + b * 16 + ln];
            #pragma unroll
            for (int a = 0; a < 2; ++a)
                #pragma unroll
                for (int b = 0; b < 7; ++b)
                    acc[a][b] = __builtin_amdgcn_mfma_f32_16x16x32_bf16(
                        af[a], bf[b], acc[a][b], 0, 0, 0);
        }
        __syncthreads();
    }

    // epilogue: hist(raw) + clamp -> bf16 o1T (padded channels-last)
    ushort_t* oimg = o1T + (size_t)n * O1_IMG;
    #pragma unroll
    for (int a = 0; a < 2; ++a) {
        int co = by * 128 + wv * 32 + a * 16 + quad * 4;
        #pragma unroll
        for (int b = 0; b < 7; ++b) {
            int p = b * 16 + ln;
            int hq = h0 + p / 28, wq = p % 28;
            ushort_t pk[4];
            #pragma unroll
            for (int r = 0; r < 4; ++r) {
                float v = acc[a][b][r];
                int bin = (int)((v - BIN_LO) * BIN_INV);
                bin = min(max(bin, 0), NBINS - 1);
                atomicAdd(&hist[bin], 1u);
                pk[r] = f2bf(fminf(fmaxf(v, 0.f), 1.f));
            }
            uint2 u; u.x = (uint_t)pk[0] | ((uint_t)pk[1] << 16);
            u.y = (uint_t)pk[2] | ((uint_t)pk[3] << 16);
            *(uint2*)(oimg + ((hq + 1) * 30 + (wq + 1)) * 256 + co) = u;
        }
    }

    __syncthreads();
    size_t blin = (size_t)(by * 448 + bx) * NBINS;
    for (int i = tid; i < NBINS; i += 256) bh[blin + i] = (ushort_t)hist[i];
}

// ---------------------------------------------------------------------------
// conv2 + fused identity. Per ci-chunk (4 x 64): stage a 6row x 32col x 64ci
// input patch in LDS once; 9 taps read shifted views. A double-buffered,
// one barrier per tap with prefetch-after-barrier. Then 2 identity stages
// from xT (stride-2 centers).
// ---------------------------------------------------------------------------
__global__ __launch_bounds__(256, 2) void conv2_mfma(
    const ushort_t* __restrict__ o1T, const ushort_t* __restrict__ xT,
    const ushort_t* __restrict__ wT2, float* __restrict__ fout,
    ushort_t* __restrict__ bh)
{
    const int bx = blockIdx.x, by = blockIdx.y;
    const int tid = threadIdx.x;
    const int wv = tid >> 6, lane = tid & 63;
    const int ln = lane & 15, quad = lane >> 4;
    const int n = bx / 7, rg = bx % 7, h0 = rg * 4;

    __shared__ short8 Ad[2 * 1024];     // 32 KB
    __shared__ short8 Bp[1536];         // 24 KB  patch [ci8 0..7][pos 0..191]
    __shared__ uint_t hist[NBINS];      // 8 KB

    for (int i = tid; i < NBINS; i += 256) hist[i] = 0;

    f32x4 acc[2][7];
    #pragma unroll
    for (int a = 0; a < 2; ++a)
        #pragma unroll
        for (int b = 0; b < 7; ++b) acc[a][b] = (f32x4){0.f, 0.f, 0.f, 0.f};

    // per-b fragment position constants
    int rw[7], pp[7];
    #pragma unroll
    for (int b = 0; b < 7; ++b) {
        int p = b * 16 + ln;
        rw[b] = (p / 28) * 32 + (p % 28);   // patch offset (row-local*32 + wq)
        pp[b] = p;                           // id-tile offset
    }

    // patch staging constants: 24 wave-insts, j = jj*4+wv
    uint_t poff[6], pdst[6];
    #pragma unroll
    for (int jj = 0; jj < 6; ++jj) {
        int j = jj * 4 + wv;
        int ci8 = j / 3, part = j - ci8 * 3;
        int pos = part * 64 + lane;
        poff[jj] = (uint_t)((h0 + (pos >> 5)) * O1_ROW + (pos & 31) * 256 + ci8 * 8);
        pdst[jj] = (uint_t)((ci8 * 192 + part * 64) * 16);
    }
    // identity staging constants: 16 wave-insts, layout [ci8][pos 0..127]
    uint_t idoff[4], idst[4];
    #pragma unroll
    for (int jj = 0; jj < 4; ++jj) {
        int j = jj * 4 + wv;
        int ci8 = j >> 1, posb = (j & 1) * 64;
        int pos = min(posb + lane, 111);
        int hh = h0 + pos / 28, ww = pos % 28;
        idoff[jj] = (uint_t)(((2 * hh + 1) * 57 + (2 * ww + 1)) * 128 + ci8 * 8);
        idst[jj] = (uint_t)((ci8 * 128 + posb) * 16);
    }

    const ushort_t* Abase = wT2 + (size_t)(by * 128 + lane) * 2432;
    const ushort_t* o1img = o1T + (size_t)n * O1_IMG;
    const ushort_t* xTimg = xT + (size_t)n * XT_IMG;

    auto stageA = [&](int k0, int buf) {
        #pragma unroll
        for (int j = 0; j < 4; ++j)
            gll16(Abase + (j & 1) * 64 * 2432 + (wv * 2 + (j >> 1)) * 8 + k0,
                  (char*)Ad + buf * 16384 + (wv * 4 + j) * 1024);
    };

    for (int c = 0; c < 4; ++c) {
        // chunk head: stage patch + first tap's A, then stall barrier
        #pragma unroll
        for (int jj = 0; jj < 6; ++jj)
            gll16(o1img + poff[jj] + c * 64, (char*)Bp + pdst[jj]);
        stageA(c * 64, (c * 9) & 1);
        __syncthreads();

        for (int t = 0; t < 9; ++t) {
            const int st = c * 9 + t;
            if (t < 8) stageA((t + 1) * 256 + c * 64, (st + 1) & 1);
            const int ab = (st & 1) * 1024;
            const int kh = t / 3, kw = t - kh * 3;
            const int tb = kh * 32 + kw;
            #pragma unroll
            for (int kk = 0; kk < 2; ++kk) {
                short8 af[2], bf[7];
                #pragma unroll
                for (int a = 0; a < 2; ++a)
                    af[a] = Ad[ab + (kk * 4 + quad) * 128 + wv * 32 + a * 16 + ln];
                #pragma unroll
                for (int b = 0; b < 7; ++b)
                    bf[b] = Bp[(kk * 4 + quad) * 192 + rw[b] + tb];
                #pragma unroll
                for (int a = 0; a < 2; ++a)
                    #pragma unroll
                    for (int b = 0; b < 7; ++b)
                        acc[a][b] = __builtin_amdgcn_mfma_f32_16x16x32_bf16(
                            af[a], bf[b], acc[a][b], 0, 0, 0);
            }
            __syncthreads();
        }
    }

    // identity: 2 stages of 64 ci from xT centers
    for (int cid = 0; cid < 2; ++cid) {
        #pragma unroll
        for (int jj = 0; jj < 4; ++jj)
            gll16(xTimg + idoff[jj] + cid * 64, (char*)Bp + idst[jj]);
        stageA(2304 + cid * 64, (36 + cid) & 1);
        __syncthreads();

        const int ab = ((36 + cid) & 1) * 1024;
        #pragma unroll
        for (int kk = 0; kk < 2; ++kk) {
            short8 af[2], bf[7];
            #pragma unroll
            for (int a = 0; a < 2; ++a)
                af[a] = Ad[ab + (kk * 4 + quad) * 128 + wv * 32 + a * 16 + ln];
            #pragma unroll
            for (int b = 0; b < 7; ++b)
                bf[b] = Bp[(kk * 4 + quad) * 128 + pp[b]];
            #pragma unroll
            for (int a = 0; a < 2; ++a)
                #pragma unroll
                for (int b = 0; b < 7; ++b)
                    acc[a][b] = __builtin_amdgcn_mfma_f32_16x16x32_bf16(
                        af[a], bf[b], acc[a][b], 0, 0, 0);
        }
        __syncthreads();
    }

    // epilogue: hist(raw) + clamp -> f32 out (NCHW)
    #pragma unroll
    for (int a = 0; a < 2; ++a) {
        #pragma unroll
        for (int b = 0; b < 7; ++b) {
            int pos = b * 16 + ln;
            #pragma unroll
            for (int r = 0; r < 4; ++r) {
                float v = acc[a][b][r];
                int bin = (int)((v - BIN_LO) * BIN_INV);
                bin = min(max(bin, 0), NBINS - 1);
                atomicAdd(&hist[bin], 1u);
                int co = by * 128 + wv * 32 + a * 16 + quad * 4 + r;
                fout[((size_t)(n * 256 + co)) * SPATIAL + h0 * 28 + pos] =
                    fminf(fmaxf(v, 0.f), 1.f);
            }
        }
    }

    __syncthreads();
    size_t blin = (size_t)(by * 448 + bx) * NBINS;
    for (int i = tid; i < NBINS; i += 256) bh[blin + i] = (ushort_t)hist[i];
}

// ---------------------------------------------------------------------------
// Reduce 896 per-block u16 histograms -> final u32 histogram
// ---------------------------------------------------------------------------
__global__ __launch_bounds__(256) void hreduce(
    const ushort_t* __restrict__ bh, uint_t* __restrict__ hf)
{
    __shared__ uint_t p[256];
    int b0 = blockIdx.x * 64;
    int binl = threadIdx.x & 63, grp = threadIdx.x >> 6;
    uint_t s = 0;
    for (int j = grp; j < 896; j += 4) s += bh[(size_t)j * NBINS + b0 + binl];
    p[threadIdx.x] = s;
    __syncthreads();
    if (threadIdx.x < 64)
        hf[b0 + threadIdx.x] = p[threadIdx.x] + p[64 + threadIdx.x] +
                               p[128 + threadIdx.x] + p[192 + threadIdx.x];
}

// ---------------------------------------------------------------------------
// Select 99 percentile values from the 2048-bin histogram
// ---------------------------------------------------------------------------
__global__ __launch_bounds__(1024) void select_k(
    const uint_t* __restrict__ hf, float* __restrict__ outp)
{
    __shared__ uint_t cs[1024];
    int t = threadIdx.x;
    uint_t s = hf[2 * t] + hf[2 * t + 1];
    cs[t] = s;
    __syncthreads();
    for (int d = 1; d < 1024; d <<= 1) {
        uint_t v = (t >= d) ? cs[t - d] : 0;
        __syncthreads();
        cs[t] += v;
        __syncthreads();
    }
    if (t >= 1 && t <= 99) {
        long long k = 1 + (long long)llrint(0.01 * (double)t * (double)(OUT_ELEMS - 1));
        int lo = 0, hi = 1023;
        while (lo < hi) { int mid = (lo + hi) >> 1; if ((long long)cs[mid] < k) lo = mid + 1; else hi = mid; }
        long long cum = (lo == 0) ? 0 : (long long)cs[lo - 1];
        int b = lo * 2;
        while (cum + (long long)hf[b] < k) { cum += hf[b]; ++b; }
        outp[t - 1] = BIN_LO + ((float)b + 0.5f) * BIN_W;
    }
}

// ---------------------------------------------------------------------------
extern "C" void kernel_launch(void* const* d_in, const int* in_sizes, int n_in,
                              void* d_out, int out_size, void* d_ws, size_t ws_size,
                              hipStream_t stream)
{
    const float* x   = (const float*)d_in[0];
    const float* w1  = (const float*)d_in[1];
    const float* w2  = (const float*)d_in[2];
    const float* wid = (const float*)d_in[3];
    float* out = (float*)d_out;

    char* ws = (char*)d_ws;
    ushort_t* xT  = (ushort_t*)ws;                         // 53,231,616 B
    ushort_t* o1T = (ushort_t*)(ws + 53231616);            // 29,495,296 B (incl pad)
    ushort_t* wT1 = (ushort_t*)(ws + 82726912);            //    589,824 B
    ushort_t* wT2 = (ushort_t*)(ws + 83316736);            //  1,245,184 B
    ushort_t* bh  = (ushort_t*)(ws + 84561920);            //  3,670,016 B
    uint_t*   hf  = (uint_t*)  (ws + 88231936);            //      8,192 B

    hipMemsetAsync(xT, 0, 53231616, stream);
    hipMemsetAsync(o1T, 0, 29495296, stream);

    wtrans<<<2432, 256, 0, stream>>>(w1, w2, wid, wT1, wT2);
    xtrans<<<dim3(14, 64), 256, 0, stream>>>(x, xT);

    conv1_mfma<<<dim3(448, 2), 256, 0, stream>>>(xT, wT1, o1T, bh);
    hreduce<<<32, 256, 0, stream>>>(bh, hf);
    select_k<<<1, 1024, 0, stream>>>(hf, out + OUT_ELEMS);

    conv2_mfma<<<dim3(448, 2), 256, 0, stream>>>(o1T, xT, wT2, out, bh);
    hreduce<<<32, 256, 0, stream>>>(bh, hf);
    select_k<<<1, 1024, 0, stream>>>(hf, out + OUT_ELEMS + 99);
}

// Round 4
// 420.600 us; speedup vs baseline: 16.6196x; 1.1107x over previous
//
#include <hip/hip_runtime.h>

typedef unsigned short ushort_t;
typedef unsigned int uint_t;

using short8 = __attribute__((ext_vector_type(8))) short;
using f32x4  = __attribute__((ext_vector_type(4))) float;

#define N_BATCH   64
#define C_MID     256
#define H_OUT     28
#define W_OUT     28
#define SPATIAL   (H_OUT*W_OUT)
#define OUT_ELEMS (N_BATCH*C_MID*SPATIAL)   // 12,845,056

// histogram: 2048 bins over [-16,16), width 1/64
#define NBINS 2048
#define BIN_LO (-16.0f)
#define BIN_INV 64.0f
#define BIN_W  0.015625f

// padded channels-last geometry (u16 element units)
#define XT_ROW   (57*128)        // 7296
#define XT_IMG   (57*57*128)     // 415872
#define O1_ROW   (30*256)        // 7680
#define O1_IMG   (30*30*256)     // 230400

__device__ __forceinline__ ushort_t f2bf(float f) {
    uint_t u = __float_as_uint(f);
    u += 0x7FFFu + ((u >> 16) & 1u);
    return (ushort_t)(u >> 16);
}

__device__ __forceinline__ void gll16(const ushort_t* g, void* l) {
    __builtin_amdgcn_global_load_lds(
        (const __attribute__((address_space(1))) unsigned int*)g,
        (__attribute__((address_space(3))) unsigned int*)l, 16, 0, 0);
}

// ---------------------------------------------------------------------------
// Zero only the border cells of xT (row0, col0) and o1T (rows 0/29, cols 0/29).
// Interior is fully rewritten by xtrans / conv1 every launch.
// Per n: xT 7232 u32  +  o1T 14848 u32  = 22080 u32.
// ---------------------------------------------------------------------------
__global__ __launch_bounds__(256) void zero_borders(
    uint_t* __restrict__ xT32, uint_t* __restrict__ o1T32)
{
    int i = blockIdx.x * 256 + threadIdx.x;
    int n = blockIdx.y;
    if (i >= 22080) return;
    if (i < 7232) {
        uint_t* base = xT32 + (size_t)n * (XT_IMG / 2);
        if (i < 3648) base[i] = 0;                              // row 0
        else { int j = i - 3648; int r = (j >> 6) + 1;          // col 0, rows 1..56
               base[r * (XT_ROW / 2) + (j & 63)] = 0; }
    } else {
        int k = i - 7232;
        uint_t* base = o1T32 + (size_t)n * (O1_IMG / 2);
        if (k < 3840) base[k] = 0;                              // row 0
        else if (k < 7680) base[29 * (O1_ROW / 2) + (k - 3840)] = 0;  // row 29
        else if (k < 11264) { int j = k - 7680; int r = (j >> 7) + 1;
               base[r * (O1_ROW / 2) + (j & 127)] = 0; }        // col 0
        else { int j = k - 11264; int r = (j >> 7) + 1;
               base[r * (O1_ROW / 2) + 29 * 128 + (j & 127)] = 0; } // col 29
    }
}

// ---------------------------------------------------------------------------
// Weight transform: wT1[co][(kh*3+kw)*128+ci] ; wT2[co][k] with k<2304 from w2
// ((kh*3+kw)*256+ci) and k in [2304,2432) = wid[co][ci].  bf16.
// ---------------------------------------------------------------------------
__global__ __launch_bounds__(256) void wtrans(
    const float* __restrict__ w1, const float* __restrict__ w2,
    const float* __restrict__ wid, ushort_t* __restrict__ wT1,
    ushort_t* __restrict__ wT2)
{
    int idx = blockIdx.x * 256 + threadIdx.x;
    if (idx < 256 * 1152) {
        int co = idx / 1152, k = idx % 1152;
        int g = k >> 7, ci = k & 127;
        wT1[idx] = f2bf(w1[(co * 128 + ci) * 9 + g]);
    }
    if (idx < 256 * 2432) {
        int co = idx / 2432, k = idx % 2432;
        float v;
        if (k < 2304) { int g = k >> 8, ci = k & 255; v = w2[(co * 256 + ci) * 9 + g]; }
        else          { v = wid[co * 128 + (k - 2304)]; }
        wT2[idx] = f2bf(v);
    }
}

// ---------------------------------------------------------------------------
// x transform: NCHW f32 -> padded channels-last bf16 xT[n][1+ih][1+iw][ci]
// ---------------------------------------------------------------------------
__global__ __launch_bounds__(256) void xtrans(
    const float* __restrict__ x, ushort_t* __restrict__ xT)
{
    __shared__ ushort_t t[224 * 130];
    const int tid = threadIdx.x;
    const int g = blockIdx.x, n = blockIdx.y;
    const float* xs = x + ((size_t)n * 128) * 3136 + g * 4 * 56;

    for (int it = 0; it < 112; ++it) {
        int f = it * 256 + tid;
        int ci = f / 224, rem = f % 224;
        t[rem * 130 + ci] = f2bf(xs[ci * 3136 + rem]);
    }
    __syncthreads();
    ushort_t* xo = xT + (size_t)n * XT_IMG + (g * 4 + 1) * XT_ROW + 128;
    for (int it = 0; it < 56; ++it) {
        int f = it * 256 + tid;
        int pos = f >> 6, c2 = f & 63;
        int r = pos / 56, iw = pos % 56;
        uint_t v = *(const uint_t*)&t[pos * 130 + c2 * 2];
        *(uint_t*)(xo + r * XT_ROW + iw * 128 + c2 * 2) = v;
    }
}

// ---------------------------------------------------------------------------
// conv1: unchanged from R3. 128co x 112pos tile, 18 stages, A+B dbuf.
// ---------------------------------------------------------------------------
__global__ __launch_bounds__(256, 2) void conv1_mfma(
    const ushort_t* __restrict__ xT, const ushort_t* __restrict__ wT1,
    ushort_t* __restrict__ o1T, ushort_t* __restrict__ bh)
{
    const int bx = blockIdx.x, by = blockIdx.y;
    const int tid = threadIdx.x;
    const int wv = tid >> 6, lane = tid & 63;
    const int ln = lane & 15, quad = lane >> 4;
    const int n = bx / 7, rg = bx % 7, h0 = rg * 4;

    __shared__ short8 Ald[2 * 1024];
    __shared__ short8 Bld[2 * 896];
    __shared__ uint_t hist[NBINS];

    for (int i = tid; i < NBINS; i += 256) hist[i] = 0;

    f32x4 acc[2][7];
    #pragma unroll
    for (int a = 0; a < 2; ++a)
        #pragma unroll
        for (int b = 0; b < 7; ++b) acc[a][b] = (f32x4){0.f, 0.f, 0.f, 0.f};

    uint_t boff[4]; int bok[4];
    #pragma unroll
    for (int j = 0; j < 4; ++j) {
        int inst = wv + 4 * j;
        int flat = inst * 64 + lane;
        int k8 = flat / 112, pos = flat % 112;
        bok[j] = (inst < 14);
        int hh = h0 + pos / 28, w = pos % 28;
        boff[j] = (uint_t)((2 * hh) * XT_ROW + (2 * w) * 128 + k8 * 8);
    }
    const ushort_t* Abase = wT1 + (size_t)(by * 128 + lane) * 1152;
    const ushort_t* Bimg = xT + (size_t)n * XT_IMG;

    auto stageA = [&](int k0, int buf) {
        #pragma unroll
        for (int j = 0; j < 4; ++j)
            gll16(Abase + (j & 1) * 64 * 1152 + (wv * 2 + (j >> 1)) * 8 + k0,
                  (char*)Ald + buf * 16384 + (wv * 4 + j) * 1024);
    };
    auto stageB = [&](int bso, int buf) {
        #pragma unroll
        for (int j = 0; j < 4; ++j)
            if (bok[j])
                gll16(Bimg + boff[j] + bso,
                      (char*)Bld + buf * 14336 + (wv + 4 * j) * 1024);
    };

    stageA(0, 0);
    stageB(0, 0);
    __syncthreads();

    for (int s = 0; s < 18; ++s) {
        if (s < 17) {
            int s1 = s + 1;
            int g = s1 >> 1, ci0 = (s1 & 1) << 6;
            int kh = g / 3, kw = g % 3;
            stageA(s1 * 64, s1 & 1);
            stageB((kh * 57 + kw) * 128 + ci0, s1 & 1);
        }
        const int ab = (s & 1) * 1024, bb = (s & 1) * 896;
        #pragma unroll
        for (int kk = 0; kk < 2; ++kk) {
            short8 af[2], bf[7];
            #pragma unroll
            for (int a = 0; a < 2; ++a)
                af[a] = Ald[ab + (kk * 4 + quad) * 128 + wv * 32 + a * 16 + ln];
            #pragma unroll
            for (int b = 0; b < 7; ++b)
                bf[b] = Bld[bb + (kk * 4 + quad) * 112 + b * 16 + ln];
            #pragma unroll
            for (int a = 0; a < 2; ++a)
                #pragma unroll
                for (int b = 0; b < 7; ++b)
                    acc[a][b] = __builtin_amdgcn_mfma_f32_16x16x32_bf16(
                        af[a], bf[b], acc[a][b], 0, 0, 0);
        }
        __syncthreads();
    }

    ushort_t* oimg = o1T + (size_t)n * O1_IMG;
    #pragma unroll
    for (int a = 0; a < 2; ++a) {
        int co = by * 128 + wv * 32 + a * 16 + quad * 4;
        #pragma unroll
        for (int b = 0; b < 7; ++b) {
            int p = b * 16 + ln;
            int hq = h0 + p / 28, wq = p % 28;
            ushort_t pk[4];
            #pragma unroll
            for (int r = 0; r < 4; ++r) {
                float v = acc[a][b][r];
                int bin = (int)((v - BIN_LO) * BIN_INV);
                bin = min(max(bin, 0), NBINS - 1);
                atomicAdd(&hist[bin], 1u);
                pk[r] = f2bf(fminf(fmaxf(v, 0.f), 1.f));
            }
            uint2 u; u.x = (uint_t)pk[0] | ((uint_t)pk[1] << 16);
            u.y = (uint_t)pk[2] | ((uint_t)pk[3] << 16);
            *(uint2*)(oimg + ((hq + 1) * 30 + (wq + 1)) * 256 + co) = u;
        }
    }

    __syncthreads();
    size_t blin = (size_t)(by * 448 + bx) * NBINS;
    for (int i = tid; i < NBINS; i += 256) bh[blin + i] = (ushort_t)hist[i];
}

// ---------------------------------------------------------------------------
// conv2 + fused identity, 8-row blocks.
// Block = 128co x 224pos (8 rows), 4 waves of 64co x 112pos (a=4, b=7).
// Per ci-chunk: 10x32x64ci patch (40KB) staged once; 9 taps, A dbuf 2x16KB,
// one barrier per tap. Tail rg=3 gated on h<28 with clamped addressing.
// ---------------------------------------------------------------------------
__global__ __launch_bounds__(256, 2) void conv2_mfma(
    const ushort_t* __restrict__ o1T, const ushort_t* __restrict__ xT,
    const ushort_t* __restrict__ wT2, float* __restrict__ fout,
    ushort_t* __restrict__ bh)
{
    const int bx = blockIdx.x;           // n*4 + rg
    const int by = blockIdx.y;
    const int tid = threadIdx.x;
    const int wv = tid >> 6, lane = tid & 63;
    const int ln = lane & 15, quad = lane >> 4;
    const int n = bx >> 2, rg = bx & 3, r0 = rg * 8;
    const int coh = wv & 1;              // co-half within 128
    const int pt  = wv >> 1;             // pos-tile (4 rows each)

    __shared__ short8 Ad[2 * 1024];      // 32 KB [buf][k8][co]
    __shared__ short8 Bp[2560];          // 40 KB patch [ci8][dr 10][col 32]
    __shared__ uint_t hist[NBINS];       // 8 KB

    for (int i = tid; i < NBINS; i += 256) hist[i] = 0;

    f32x4 acc[4][7];
    #pragma unroll
    for (int a = 0; a < 4; ++a)
        #pragma unroll
        for (int b = 0; b < 7; ++b) acc[a][b] = (f32x4){0.f, 0.f, 0.f, 0.f};

    // per-b position constants
    int prb[7], cl0[7], hlog[7];
    #pragma unroll
    for (int b = 0; b < 7; ++b) {
        int p = b * 16 + ln;
        int h = r0 + pt * 4 + p / 28;
        hlog[b] = h;
        prb[b] = (min(h, 27) - r0) * 32;
        cl0[b] = p % 28;
    }

    // patch staging offsets: inst = wv*10+jj ; f = inst*64+lane
    uint_t po[10];
    #pragma unroll
    for (int jj = 0; jj < 10; ++jj) {
        int f = (wv * 10 + jj) * 64 + lane;
        int ci8 = f / 320, rem = f % 320;
        int dr = rem >> 5, cl = rem & 31;
        po[jj] = (uint_t)(min(r0 + dr, 29) * O1_ROW + cl * 256 + ci8 * 8);
    }
    // identity staging offsets: inst = wv*7+jj ; layout [ci8][pos 224]
    uint_t io[7];
    #pragma unroll
    for (int jj = 0; jj < 7; ++jj) {
        int f = (wv * 7 + jj) * 64 + lane;
        int ci8 = f / 224, pos = f % 224;
        int h = min(r0 + pos / 28, 27), w = pos % 28;
        io[jj] = (uint_t)(((2 * h + 1) * 57 + (2 * w + 1)) * 128 + ci8 * 8);
    }

    const ushort_t* Abase = wT2 + (size_t)(by * 128 + lane) * 2432;
    const ushort_t* o1img = o1T + (size_t)n * O1_IMG;
    const ushort_t* xTimg = xT + (size_t)n * XT_IMG;

    auto stageA = [&](int k0, int buf) {
        #pragma unroll
        for (int j = 0; j < 4; ++j)
            gll16(Abase + (j & 1) * 64 * 2432 + (wv * 2 + (j >> 1)) * 8 + k0,
                  (char*)Ad + buf * 16384 + (wv * 4 + j) * 1024);
    };

    for (int c = 0; c < 4; ++c) {
        // patch free here (hist-init or prev tap's barrier)
        #pragma unroll
        for (int jj = 0; jj < 10; ++jj)
            gll16(o1img + po[jj] + c * 64, (char*)Bp + (wv * 10 + jj) * 1024);
        if (c == 0) stageA(0, 0);
        __syncthreads();

        for (int t = 0; t < 9; ++t) {
            const int as = c * 9 + t;
            if (t < 8)      stageA((t + 1) * 256 + c * 64, (as + 1) & 1);
            else if (c < 3) stageA(c * 64 + 64, (as + 1) & 1);   // next chunk tap0
            else            stageA(2304, (as + 1) & 1);          // id0
            const int ab = (as & 1) * 1024;
            const int kh = t / 3, kw = t - kh * 3;
            #pragma unroll
            for (int kk = 0; kk < 2; ++kk) {
                short8 af[4], bf[7];
                #pragma unroll
                for (int a = 0; a < 4; ++a)
                    af[a] = Ad[ab + (kk * 4 + quad) * 128 + coh * 64 + a * 16 + ln];
                #pragma unroll
                for (int b = 0; b < 7; ++b)
                    bf[b] = Bp[(kk * 4 + quad) * 320 + prb[b] + kh * 32 + cl0[b] + kw];
                #pragma unroll
                for (int a = 0; a < 4; ++a)
                    #pragma unroll
                    for (int b = 0; b < 7; ++b)
                        acc[a][b] = __builtin_amdgcn_mfma_f32_16x16x32_bf16(
                            af[a], bf[b], acc[a][b], 0, 0, 0);
            }
            __syncthreads();
        }
    }

    // identity: 2 stages of 64 ci from xT centers
    for (int cid = 0; cid < 2; ++cid) {
        #pragma unroll
        for (int jj = 0; jj < 7; ++jj)
            gll16(xTimg + io[jj] + cid * 64, (char*)Bp + (wv * 7 + jj) * 1024);
        __syncthreads();
        if (cid == 0) stageA(2368, 1);
        const int ab = ((36 + cid) & 1) * 1024;
        #pragma unroll
        for (int kk = 0; kk < 2; ++kk) {
            short8 af[4], bf[7];
            #pragma unroll
            for (int a = 0; a < 4; ++a)
                af[a] = Ad[ab + (kk * 4 + quad) * 128 + coh * 64 + a * 16 + ln];
            #pragma unroll
            for (int b = 0; b < 7; ++b)
                bf[b] = Bp[(kk * 4 + quad) * 224 + pt * 112 + b * 16 + ln];
            #pragma unroll
            for (int a = 0; a < 4; ++a)
                #pragma unroll
                for (int b = 0; b < 7; ++b)
                    acc[a][b] = __builtin_amdgcn_mfma_f32_16x16x32_bf16(
                        af[a], bf[b], acc[a][b], 0, 0, 0);
        }
        __syncthreads();
    }

    // epilogue: hist(raw) + clamp -> f32 out (NCHW), gated on valid rows
    #pragma unroll
    for (int a = 0; a < 4; ++a) {
        int co = by * 128 + coh * 64 + a * 16 + quad * 4;
        #pragma unroll
        for (int b = 0; b < 7; ++b) {
            if (hlog[b] <= 27) {
                #pragma unroll
                for (int r = 0; r < 4; ++r) {
                    float v = acc[a][b][r];
                    int bin = (int)((v - BIN_LO) * BIN_INV);
                    bin = min(max(bin, 0), NBINS - 1);
                    atomicAdd(&hist[bin], 1u);
                    fout[((size_t)(n * 256 + co + r)) * SPATIAL +
                         hlog[b] * 28 + cl0[b]] = fminf(fmaxf(v, 0.f), 1.f);
                }
            }
        }
    }

    __syncthreads();
    size_t blin = (size_t)(by * 256 + bx) * NBINS;
    for (int i = tid; i < NBINS; i += 256) bh[blin + i] = (ushort_t)hist[i];
}

// ---------------------------------------------------------------------------
// Reduce nblk per-block u16 histograms -> final u32 histogram
// ---------------------------------------------------------------------------
__global__ __launch_bounds__(256) void hreduce(
    const ushort_t* __restrict__ bh, uint_t* __restrict__ hf, int nblk)
{
    __shared__ uint_t p[256];
    int b0 = blockIdx.x * 64;
    int binl = threadIdx.x & 63, grp = threadIdx.x >> 6;
    uint_t s = 0;
    for (int j = grp; j < nblk; j += 4) s += bh[(size_t)j * NBINS + b0 + binl];
    p[threadIdx.x] = s;
    __syncthreads();
    if (threadIdx.x < 64)
        hf[b0 + threadIdx.x] = p[threadIdx.x] + p[64 + threadIdx.x] +
                               p[128 + threadIdx.x] + p[192 + threadIdx.x];
}

// ---------------------------------------------------------------------------
// Select 99 percentile values from the 2048-bin histogram
// ---------------------------------------------------------------------------
__global__ __launch_bounds__(1024) void select_k(
    const uint_t* __restrict__ hf, float* __restrict__ outp)
{
    __shared__ uint_t cs[1024];
    int t = threadIdx.x;
    uint_t s = hf[2 * t] + hf[2 * t + 1];
    cs[t] = s;
    __syncthreads();
    for (int d = 1; d < 1024; d <<= 1) {
        uint_t v = (t >= d) ? cs[t - d] : 0;
        __syncthreads();
        cs[t] += v;
        __syncthreads();
    }
    if (t >= 1 && t <= 99) {
        long long k = 1 + (long long)llrint(0.01 * (double)t * (double)(OUT_ELEMS - 1));
        int lo = 0, hi = 1023;
        while (lo < hi) { int mid = (lo + hi) >> 1; if ((long long)cs[mid] < k) lo = mid + 1; else hi = mid; }
        long long cum = (lo == 0) ? 0 : (long long)cs[lo - 1];
        int b = lo * 2;
        while (cum + (long long)hf[b] < k) { cum += hf[b]; ++b; }
        outp[t - 1] = BIN_LO + ((float)b + 0.5f) * BIN_W;
    }
}

// ---------------------------------------------------------------------------
extern "C" void kernel_launch(void* const* d_in, const int* in_sizes, int n_in,
                              void* d_out, int out_size, void* d_ws, size_t ws_size,
                              hipStream_t stream)
{
    const float* x   = (const float*)d_in[0];
    const float* w1  = (const float*)d_in[1];
    const float* w2  = (const float*)d_in[2];
    const float* wid = (const float*)d_in[3];
    float* out = (float*)d_out;

    char* ws = (char*)d_ws;
    ushort_t* xT  = (ushort_t*)ws;                         // 53,231,616 B (+4K pad)
    ushort_t* o1T = (ushort_t*)(ws + 53235712);            // 29,491,200 B (+4K pad)
    ushort_t* wT1 = (ushort_t*)(ws + 82731008);            //    589,824 B
    ushort_t* wT2 = (ushort_t*)(ws + 83320832);            //  1,245,184 B
    ushort_t* bh  = (ushort_t*)(ws + 84566016);            //  3,670,016 B
    uint_t*   hf  = (uint_t*)  (ws + 88236032);            //      8,192 B

    zero_borders<<<dim3(87, 64), 256, 0, stream>>>((uint_t*)xT, (uint_t*)o1T);
    wtrans<<<2432, 256, 0, stream>>>(w1, w2, wid, wT1, wT2);
    xtrans<<<dim3(14, 64), 256, 0, stream>>>(x, xT);

    conv1_mfma<<<dim3(448, 2), 256, 0, stream>>>(xT, wT1, o1T, bh);
    hreduce<<<32, 256, 0, stream>>>(bh, hf, 896);
    select_k<<<1, 1024, 0, stream>>>(hf, out + OUT_ELEMS);

    conv2_mfma<<<dim3(256, 2), 256, 0, stream>>>(o1T, xT, wT2, out, bh);
    hreduce<<<32, 256, 0, stream>>>(bh, hf, 512);
    select_k<<<1, 1024, 0, stream>>>(hf, out + OUT_ELEMS + 99);
}